// Round 12
// baseline (540.763 us; speedup 1.0000x reference)
//
#include <hip/hip_runtime.h>
#include <hip/hip_cooperative_groups.h>

namespace cg = cooperative_groups;

typedef unsigned short u16;
typedef u16   u16x8 __attribute__((ext_vector_type(8)));
typedef short s16x8 __attribute__((ext_vector_type(8)));
typedef float f32x4 __attribute__((ext_vector_type(4)));

__device__ __forceinline__ float b2f(u16 u) {
    return __uint_as_float(((unsigned)u) << 16);
}
__device__ __forceinline__ u16 f2b(float f) {
    unsigned x = __float_as_uint(f);
    x += 0x7fffu + ((x >> 16) & 1u);
    return (u16)(x >> 16);
}
__device__ __forceinline__ void gload_lds(const u16* g, u16* l) {
    __builtin_amdgcn_global_load_lds(
        (const __attribute__((address_space(1))) unsigned int*)g,
        (__attribute__((address_space(3))) unsigned int*)l, 16, 0, 0);
}

#define THETA_SCALE 0.05190512648261f   // log2(10000)/256

// ============================================================================
// Phase bodies (shared by fused cooperative kernel and fallback kernels)
// ============================================================================

__device__ __forceinline__ void prep_cast(const float* __restrict__ X,
                                          u16* __restrict__ Xb, int unit, int t) {
    size_t i = (size_t)unit * 2048 + (size_t)t * 8;
    float4 a = *(const float4*)(X + i);
    float4 b = *(const float4*)(X + i + 4);
    u16x8 r;
    r[0] = f2b(a.x); r[1] = f2b(a.y); r[2] = f2b(a.z); r[3] = f2b(a.w);
    r[4] = f2b(b.x); r[5] = f2b(b.y); r[6] = f2b(b.z); r[7] = f2b(b.w);
    *(u16x8*)(Xb + i) = r;
}

__device__ __forceinline__ void prep_transpose(const float* __restrict__ W,
                                               u16* __restrict__ WT,
                                               float* tile /*[32][33]*/,
                                               int bid, int t) {
    int c0 = (bid & 31) * 32;
    int r0 = (bid >> 5) * 32;
    int tx = t & 31;
    int ty = t >> 5;
    #pragma unroll
    for (int i = 0; i < 4; ++i) {
        int r = ty + i * 8;
        tile[r * 33 + tx] = W[(size_t)(r0 + r) * 1024 + c0 + tx];
    }
    __syncthreads();
    #pragma unroll
    for (int i = 0; i < 4; ++i) {
        int r = ty + i * 8;
        WT[(size_t)(c0 + r) * 512 + r0 + tx] = f2b(tile[tx * 33 + r]);
    }
}

__device__ __forceinline__ void gemm_body(const u16* __restrict__ Xb,
                                          const u16* __restrict__ WT,
                                          const float* __restrict__ bqk,
                                          u16* __restrict__ Qb,
                                          u16* __restrict__ Kb,
                                          u16* As, u16* Bs, int m0, int n0, int t) {
    const int lane = t & 63;
    const int wave = t >> 6;
    const int wm = (wave >> 1) * 64;
    const int wn = (wave & 1) * 64;
    const int quad = lane >> 4;
    const int l16 = lane & 15;
    const int lr = lane >> 3;
    const int cg2 = ((lane & 7) ^ lr) * 8;

    f32x4 acc[4][4];
    f32x4 zero4 = {0.f, 0.f, 0.f, 0.f};
    #pragma unroll
    for (int i = 0; i < 4; ++i)
        #pragma unroll
        for (int j = 0; j < 4; ++j) acc[i][j] = zero4;

    for (int k0 = 0; k0 < 512; k0 += 64) {
        __syncthreads();
        #pragma unroll
        for (int g = 0; g < 4; ++g) {
            int r0 = wave * 32 + g * 8;
            size_t ga = (size_t)(m0 + r0 + lr) * 512 + k0 + cg2;
            size_t gb = (size_t)(n0 + r0 + lr) * 512 + k0 + cg2;
            gload_lds(Xb + ga, &As[r0 * 64]);
            gload_lds(WT + gb, &Bs[r0 * 64]);
        }
        __syncthreads();
        #pragma unroll
        for (int ks = 0; ks < 64; ks += 32) {
            const int cbase = quad + (ks >> 3);
            s16x8 a4[4], b4[4];
            #pragma unroll
            for (int i = 0; i < 4; ++i) {
                int row = wm + i * 16 + l16;
                a4[i] = *(const s16x8*)&As[row * 64 + ((cbase ^ (row & 7)) * 8)];
            }
            #pragma unroll
            for (int j = 0; j < 4; ++j) {
                int row = wn + j * 16 + l16;
                b4[j] = *(const s16x8*)&Bs[row * 64 + ((cbase ^ (row & 7)) * 8)];
            }
            #pragma unroll
            for (int i = 0; i < 4; ++i)
                #pragma unroll
                for (int j = 0; j < 4; ++j)
                    acc[i][j] = __builtin_amdgcn_mfma_f32_16x16x32_bf16(
                        a4[i], b4[j], acc[i][j], 0, 0, 0);
        }
    }

    u16* O = (n0 < 512) ? Qb : Kb;   // block-uniform
    #pragma unroll
    for (int i = 0; i < 4; ++i)
        #pragma unroll
        for (int j = 0; j < 4; ++j) {
            int col = n0 + wn + j * 16 + l16;
            float bias = bqk[col];
            int gc = col & 511;
            #pragma unroll
            for (int r = 0; r < 4; ++r) {
                int grow = m0 + wm + i * 16 + quad * 4 + r;
                float v = acc[i][j][r] + bias;
                v = v > 0.f ? v + 1.f : __expf(v);   // elu(v)+1
                O[(size_t)grow * 512 + gc] = f2b(v);
            }
        }
}

// kv chunk: 32x32 GEMM over `rows` N-rows via MFMA; atomic handoff.
__device__ __forceinline__ void kv_body(const u16* __restrict__ Kb,
                                        const u16* __restrict__ Xb,
                                        float* __restrict__ kvbuf,
                                        float* __restrict__ ksum,
                                        u16* krT, u16* vT, float* red,
                                        int bh, int nb, int npass, int t) {
    const int b = bh >> 4, h = bh & 15;
    const int row = t >> 2;
    const int c8 = (t & 3) * 8;
    const int rot_w = 16 * ((c8 >> 3) & 3);
    const int lane = t & 63;
    const int wave = t >> 6;
    const int quad = lane >> 4;
    const int l16 = lane & 15;
    const int dq = (wave >> 1) * 16;
    const int eq = (wave & 1) * 16;
    const int ca = dq + l16;
    const int cb2 = eq + l16;
    const int rot_a = 16 * ((ca >> 3) & 3);
    const int rot_b = 16 * ((cb2 >> 3) & 3);

    float ksl[8] = {0, 0, 0, 0, 0, 0, 0, 0};
    f32x4 acc = {0.f, 0.f, 0.f, 0.f};
    f32x4 zero4 = {0.f, 0.f, 0.f, 0.f};

    float th[4];
    #pragma unroll
    for (int p = 0; p < 4; ++p)
        th[p] = exp2f(-THETA_SCALE * (float)(h * 16 + (c8 >> 1) + p));

    for (int pass = 0; pass < npass; ++pass) {
        int n = nb + pass * 64 + row;
        size_t base = (size_t)(b * 4096 + n) * 512 + h * 32 + c8;
        u16x8 k8 = *(const u16x8*)(Kb + base);
        u16x8 v8 = *(const u16x8*)(Xb + base);
        float kf[8], kr[8];
        #pragma unroll
        for (int j = 0; j < 8; ++j) kf[j] = b2f(k8[j]);
        #pragma unroll
        for (int p = 0; p < 4; ++p) {
            float sv, cv;
            sincosf((float)n * th[p], &sv, &cv);
            kr[2 * p]     = kf[2 * p] * cv - kf[2 * p + 1] * sv;
            kr[2 * p + 1] = kf[2 * p] * sv + kf[2 * p + 1] * cv;
        }
        #pragma unroll
        for (int j = 0; j < 8; ++j) ksl[j] += kf[j];
        __syncthreads();
        int colw = (row + rot_w) & 63;
        #pragma unroll
        for (int j = 0; j < 8; ++j) {
            krT[(c8 + j) * 72 + colw] = f2b(kr[j]);
            vT[(c8 + j) * 72 + colw] = v8[j];
        }
        __syncthreads();
        #pragma unroll
        for (int ks = 0; ks < 64; ks += 32) {
            s16x8 a4 = *(const s16x8*)&krT[ca * 72 + ((ks + quad * 8 + rot_a) & 63)];
            s16x8 b4 = *(const s16x8*)&vT[cb2 * 72 + ((ks + quad * 8 + rot_b) & 63)];
            acc = __builtin_amdgcn_mfma_f32_16x16x32_bf16(a4, b4, acc, 0, 0, 0);
        }
    }

    #pragma unroll
    for (int r = 0; r < 4; ++r)
        atomicAdd(&kvbuf[(size_t)bh * 1024 + (dq + quad * 4 + r) * 32 + eq + l16],
                  acc[r]);

    __syncthreads();
    *(float4*)&red[row * 36 + c8]     = make_float4(ksl[0], ksl[1], ksl[2], ksl[3]);
    *(float4*)&red[row * 36 + c8 + 4] = make_float4(ksl[4], ksl[5], ksl[6], ksl[7]);
    __syncthreads();
    if (t < 32) {
        float s = 0.f;
        for (int r = 0; r < 64; ++r) s += red[r * 36 + t];
        atomicAdd(&ksum[bh * 32 + t], s);
    }
}

__device__ __forceinline__ void out_body(const u16* __restrict__ Qb,
                                         const u16* __restrict__ Xb,
                                         const float* __restrict__ kvbuf,
                                         const float* __restrict__ ksum,
                                         const float* __restrict__ lw,
                                         const float* __restrict__ lb,
                                         float* __restrict__ OUT,
                                         float* kv_s, float* qr_s,
                                         float* ks_s, float* z_s,
                                         int b, int nb, int hbase, int t) {
    const int row = t >> 2;
    const int c4 = t & 3;
    const int e0 = c4 * 8;
    const float invN = 1.f / 4096.f;
    const int n = nb + row;
    const size_t rowbase = (size_t)(b * 4096 + n) * 512;

    for (int hh = 0; hh < 4; ++hh) {
        const int h = hbase + hh;
        const int bh = b * 16 + h;
        __syncthreads();
        #pragma unroll
        for (int i = 0; i < 4; ++i) {
            int id = t + i * 256;
            kv_s[(id >> 5) * 36 + (id & 31)] = kvbuf[(size_t)bh * 1024 + id] * invN;
        }
        if (t < 32) ks_s[t] = ksum[bh * 32 + t] * invN;
        __syncthreads();

        u16x8 q8 = *(const u16x8*)(Qb + rowbase + h * 32 + e0);
        float qf[8];
        #pragma unroll
        for (int j = 0; j < 8; ++j) qf[j] = b2f(q8[j]);
        float part = 0.f;
        #pragma unroll
        for (int j = 0; j < 8; ++j) part += qf[j] * ks_s[e0 + j];
        float qr[8];
        #pragma unroll
        for (int p = 0; p < 4; ++p) {
            float th = exp2f(-THETA_SCALE * (float)(h * 16 + c4 * 4 + p));
            float sv, cv;
            sincosf((float)n * th, &sv, &cv);
            qr[2 * p]     = qf[2 * p] * cv - qf[2 * p + 1] * sv;
            qr[2 * p + 1] = qf[2 * p] * sv + qf[2 * p + 1] * cv;
        }
        *(float4*)&qr_s[row * 36 + e0]     = make_float4(qr[0], qr[1], qr[2], qr[3]);
        *(float4*)&qr_s[row * 36 + e0 + 4] = make_float4(qr[4], qr[5], qr[6], qr[7]);
        part += __shfl_xor(part, 1);
        part += __shfl_xor(part, 2);
        if (c4 == 0) z_s[row] = 1.f / (part + 1e-6f);
        __syncthreads();

        float o[8] = {0, 0, 0, 0, 0, 0, 0, 0};
        #pragma unroll 4
        for (int dd = 0; dd < 32; ++dd) {
            float qd = qr_s[row * 36 + dd];
            const float4 k0v = *(const float4*)&kv_s[dd * 36 + e0];
            const float4 k1v = *(const float4*)&kv_s[dd * 36 + e0 + 4];
            o[0] += qd * k0v.x; o[1] += qd * k0v.y; o[2] += qd * k0v.z; o[3] += qd * k0v.w;
            o[4] += qd * k1v.x; o[5] += qd * k1v.y; o[6] += qd * k1v.z; o[7] += qd * k1v.w;
        }
        const float z = z_s[row];

        const int cb = h * 32 + e0;
        u16x8 xc = *(const u16x8*)(Xb + rowbase + cb);
        u16x8 xm = {0, 0, 0, 0, 0, 0, 0, 0};
        u16x8 xp = {0, 0, 0, 0, 0, 0, 0, 0};
        if (n > 0)    xm = *(const u16x8*)(Xb + rowbase - 512 + cb);
        if (n < 4095) xp = *(const u16x8*)(Xb + rowbase + 512 + cb);
        float rv[8];
        #pragma unroll
        for (int j = 0; j < 8; ++j) {
            int c = cb + j;
            float lep = b2f(xm[j]) * lw[c * 3] +
                        b2f(xc[j]) * lw[c * 3 + 1] +
                        b2f(xp[j]) * lw[c * 3 + 2] + lb[c];
            rv[j] = o[j] * z + lep;
        }
        float* Of = OUT + rowbase + cb;
        *(float4*)Of       = make_float4(rv[0], rv[1], rv[2], rv[3]);
        *(float4*)(Of + 4) = make_float4(rv[4], rv[5], rv[6], rv[7]);
    }
}

// ============================================================================
// Fused cooperative kernel: 1024 blocks x 256 threads, 4 blocks/CU
// ============================================================================
__global__ __launch_bounds__(256, 4)
void k_fused(const float* __restrict__ x, const float* __restrict__ Wqk,
             const float* __restrict__ bqk, const float* __restrict__ lw,
             const float* __restrict__ lb,
             u16* __restrict__ Xb, u16* __restrict__ WT,
             u16* __restrict__ Qb, u16* __restrict__ Kb,
             float* __restrict__ kvbuf, float* __restrict__ ksum,
             float* __restrict__ OUT) {
    __shared__ __align__(16) char smem[32768];
    const int t = threadIdx.x;
    const int blk = blockIdx.x;
    cg::grid_group grid = cg::this_grid();

    // ---- phase 1: prep (cast x4 / transpose / zero) ----
    #pragma unroll
    for (int c = 0; c < 4; ++c) prep_cast(x, Xb, blk * 4 + c, t);
    if (blk < 512) prep_transpose(Wqk, WT, (float*)smem, blk, t);
    else if (blk < 578) {
        size_t i = (size_t)(blk - 512) * 1024 + t * 4;
        *(float4*)(kvbuf + i) = make_float4(0.f, 0.f, 0.f, 0.f);   // kv+ksum contig
    }
    grid.sync();

    // ---- phase 2: QK GEMM ----
    gemm_body(Xb, WT, bqk, Qb, Kb,
              (u16*)smem, (u16*)(smem + 16384),
              (blk & 127) * 128, (blk >> 7) * 128, t);
    grid.sync();

    // ---- phase 3: kv/ksum (16 chunks x 256 rows, all blocks busy) ----
    kv_body(Kb, Xb, kvbuf, ksum,
            (u16*)smem, (u16*)(smem + 4608), (float*)(smem + 9216),
            blk & 63, (blk >> 6) * 256, 4, t);
    grid.sync();

    // ---- phase 4: out ----
    out_body(Qb, Xb, kvbuf, ksum, lw, lb, OUT,
             (float*)smem, (float*)(smem + 4608),
             (float*)(smem + 13824), (float*)(smem + 13952),
             (blk & 255) >> 6, (blk & 63) * 64, (blk >> 8) * 4, t);
}

// ============================================================================
// Fallback kernels (R10-proven 4-launch path)
// ============================================================================
__global__ __launch_bounds__(256)
void k_prep(const float* __restrict__ X, u16* __restrict__ Xb,
            const float* __restrict__ W, u16* __restrict__ WT,
            float* __restrict__ kvz) {
    if (blockIdx.x < 4096) {
        prep_cast(X, Xb, blockIdx.x, threadIdx.x);
    } else if (blockIdx.x < 4608) {
        __shared__ float tile[32 * 33];
        prep_transpose(W, WT, tile, blockIdx.x - 4096, threadIdx.x);
    } else {
        size_t i = (size_t)(blockIdx.x - 4608) * 1024 + threadIdx.x * 4;
        *(float4*)(kvz + i) = make_float4(0.f, 0.f, 0.f, 0.f);
    }
}

__global__ __launch_bounds__(256)
void k_gemm(const u16* __restrict__ Xb, const u16* __restrict__ WT,
            const float* __restrict__ bqk,
            u16* __restrict__ Qb, u16* __restrict__ Kb) {
    __shared__ u16 As[128 * 64];
    __shared__ u16 Bs[128 * 64];
    gemm_body(Xb, WT, bqk, Qb, Kb, As, Bs,
              blockIdx.x * 128, blockIdx.y * 128, threadIdx.x);
}

__global__ __launch_bounds__(256)
void k_kv(const u16* __restrict__ Kb, const u16* __restrict__ Xb,
          float* __restrict__ kvbuf, float* __restrict__ ksum) {
    __shared__ u16 krT[32 * 72];
    __shared__ u16 vT[32 * 72];
    __shared__ float red[64 * 36];
    kv_body(Kb, Xb, kvbuf, ksum, krT, vT, red,
            blockIdx.x, blockIdx.y * 512, 8, threadIdx.x);
}

__global__ __launch_bounds__(256)
void k_out(const u16* __restrict__ Qb, const u16* __restrict__ Xb,
           const float* __restrict__ kvbuf, const float* __restrict__ ksum,
           const float* __restrict__ lw, const float* __restrict__ lb,
           float* __restrict__ OUT) {
    __shared__ float kv_s[32 * 36];
    __shared__ float qr_s[64 * 36];
    __shared__ float ks_s[32];
    __shared__ float z_s[64];
    out_body(Qb, Xb, kvbuf, ksum, lw, lb, OUT, kv_s, qr_s, ks_s, z_s,
             blockIdx.x >> 6, (blockIdx.x & 63) * 64, blockIdx.y * 4,
             threadIdx.x);
}

extern "C" void kernel_launch(void* const* d_in, const int* in_sizes, int n_in,
                              void* d_out, int out_size, void* d_ws, size_t ws_size,
                              hipStream_t stream) {
    const float* x   = (const float*)d_in[0];
    const float* Wqk = (const float*)d_in[1];
    const float* bqk = (const float*)d_in[2];
    const float* lw  = (const float*)d_in[3];
    const float* lb  = (const float*)d_in[4];
    float* out = (float*)d_out;

    // workspace (~49.3 MB); kvbuf+ksum contiguous
    char* w = (char*)d_ws;
    u16* Kb      = (u16*)w;   w += (size_t)16384 * 512 * 2;   // 16 MB
    u16* Qb      = (u16*)w;   w += (size_t)16384 * 512 * 2;   // 16 MB
    u16* Xb      = (u16*)w;   w += (size_t)16384 * 512 * 2;   // 16 MB
    u16* WT      = (u16*)w;   w += (size_t)1024 * 512 * 2;    // 1 MB
    float* kvbuf = (float*)w; w += (size_t)64 * 1024 * 4;     // 256 KB
    float* ksum  = (float*)w;                                 // 8 KB (contig)

    void* args[] = {(void*)&x, (void*)&Wqk, (void*)&bqk, (void*)&lw, (void*)&lb,
                    (void*)&Xb, (void*)&WT, (void*)&Qb, (void*)&Kb,
                    (void*)&kvbuf, (void*)&ksum, (void*)&out};
    hipError_t err = hipLaunchCooperativeKernel(
        (const void*)k_fused, dim3(1024), dim3(256), args, 0, stream);
    if (err != hipSuccess) {
        // fallback: proven 4-launch path (identical numerics)
        k_prep<<<4674, 256, 0, stream>>>(x, Xb, Wqk, WT, kvbuf);
        k_gemm<<<dim3(128, 8), 256, 0, stream>>>(Xb, WT, bqk, Qb, Kb);
        k_kv<<<dim3(64, 8), 256, 0, stream>>>(Kb, Xb, kvbuf, ksum);
        k_out<<<dim3(256, 4), 256, 0, stream>>>(Qb, Xb, kvbuf, ksum, lw, lb, out);
    }
}

// Round 13
// 145.164 us; speedup vs baseline: 3.7252x; 3.7252x over previous
//
#include <hip/hip_runtime.h>

typedef unsigned short u16;
typedef u16   u16x8 __attribute__((ext_vector_type(8)));
typedef short s16x8 __attribute__((ext_vector_type(8)));
typedef float f32x4 __attribute__((ext_vector_type(4)));

__device__ __forceinline__ float b2f(u16 u) {
    return __uint_as_float(((unsigned)u) << 16);
}
__device__ __forceinline__ u16 f2b(float f) {
    unsigned x = __float_as_uint(f);
    x += 0x7fffu + ((x >> 16) & 1u);
    return (u16)(x >> 16);
}
// async global->LDS, 16B per lane; LDS dest = wave-uniform base + lane*16
__device__ __forceinline__ void gload_lds(const u16* g, u16* l) {
    __builtin_amdgcn_global_load_lds(
        (const __attribute__((address_space(1))) unsigned int*)g,
        (__attribute__((address_space(3))) unsigned int*)l, 16, 0, 0);
}

#define THETA_SCALE 0.05190512648261f   // log2(10000)/256

// ---------------- prep: Xb = bf16(x) + WT = bf16(Wqk^T) + zero kvbuf/ksum ---
__global__ __launch_bounds__(256)
void k_prep(const float* __restrict__ X, u16* __restrict__ Xb,
            const float* __restrict__ W, u16* __restrict__ WT,
            float* __restrict__ kvz) {
    if (blockIdx.x < 4096) {
        size_t i = (size_t)(blockIdx.x * 256 + threadIdx.x) * 8;
        float4 a = *(const float4*)(X + i);
        float4 b = *(const float4*)(X + i + 4);
        u16x8 r;
        r[0] = f2b(a.x); r[1] = f2b(a.y); r[2] = f2b(a.z); r[3] = f2b(a.w);
        r[4] = f2b(b.x); r[5] = f2b(b.y); r[6] = f2b(b.z); r[7] = f2b(b.w);
        *(u16x8*)(Xb + i) = r;
    } else if (blockIdx.x < 4608) {
        __shared__ float tile[32][33];
        int bid = blockIdx.x - 4096;        // 0..511 = 32 x 16
        int c0 = (bid & 31) * 32;
        int r0 = (bid >> 5) * 32;
        int tx = threadIdx.x & 31;
        int ty = threadIdx.x >> 5;
        #pragma unroll
        for (int i = 0; i < 4; ++i) {
            int r = ty + i * 8;
            tile[r][tx] = W[(size_t)(r0 + r) * 1024 + c0 + tx];
        }
        __syncthreads();
        #pragma unroll
        for (int i = 0; i < 4; ++i) {
            int r = ty + i * 8;
            WT[(size_t)(c0 + r) * 512 + r0 + tx] = f2b(tile[tx][r]);
        }
    } else {
        // zero kvbuf (65536 f) + ksum (2048 f): 66 blocks x 1024 floats
        size_t i = (size_t)(blockIdx.x - 4608) * 1024 + threadIdx.x * 4;
        *(float4*)(kvz + i) = make_float4(0.f, 0.f, 0.f, 0.f);
    }
}

// ---------------- GEMM: Xb x WT + bias, elu+1 -> Qb (bf16), Kb (bf16) -------
// LDS XOR-swizzle: LDS chunk c of row r holds global chunk c ^ (r&7)
__global__ __launch_bounds__(256)
void k_gemm(const u16* __restrict__ Xb, const u16* __restrict__ WT,
            const float* __restrict__ bqk,
            u16* __restrict__ Qb, u16* __restrict__ Kb) {
    __shared__ u16 As[128 * 64];
    __shared__ u16 Bs[128 * 64];
    const int t = threadIdx.x;
    const int m0 = blockIdx.x * 128;
    const int n0 = blockIdx.y * 128;
    const int lane = t & 63;
    const int wave = t >> 6;
    const int wm = (wave >> 1) * 64;
    const int wn = (wave & 1) * 64;
    const int quad = lane >> 4;
    const int l16 = lane & 15;
    const int lr = lane >> 3;
    const int cg = ((lane & 7) ^ lr) * 8;

    f32x4 acc[4][4];
    f32x4 zero4 = {0.f, 0.f, 0.f, 0.f};
    #pragma unroll
    for (int i = 0; i < 4; ++i)
        #pragma unroll
        for (int j = 0; j < 4; ++j) acc[i][j] = zero4;

    for (int k0 = 0; k0 < 512; k0 += 64) {
        __syncthreads();
        #pragma unroll
        for (int g = 0; g < 4; ++g) {
            int r0 = wave * 32 + g * 8;
            size_t ga = (size_t)(m0 + r0 + lr) * 512 + k0 + cg;
            size_t gb = (size_t)(n0 + r0 + lr) * 512 + k0 + cg;
            gload_lds(Xb + ga, &As[r0 * 64]);
            gload_lds(WT + gb, &Bs[r0 * 64]);
        }
        __syncthreads();
        #pragma unroll
        for (int ks = 0; ks < 64; ks += 32) {
            const int cbase = quad + (ks >> 3);
            s16x8 a4[4], b4[4];
            #pragma unroll
            for (int i = 0; i < 4; ++i) {
                int row = wm + i * 16 + l16;
                a4[i] = *(const s16x8*)&As[row * 64 + ((cbase ^ (row & 7)) * 8)];
            }
            #pragma unroll
            for (int j = 0; j < 4; ++j) {
                int row = wn + j * 16 + l16;
                b4[j] = *(const s16x8*)&Bs[row * 64 + ((cbase ^ (row & 7)) * 8)];
            }
            #pragma unroll
            for (int i = 0; i < 4; ++i)
                #pragma unroll
                for (int j = 0; j < 4; ++j)
                    acc[i][j] = __builtin_amdgcn_mfma_f32_16x16x32_bf16(
                        a4[i], b4[j], acc[i][j], 0, 0, 0);
        }
    }

    u16* O = (n0 < 512) ? Qb : Kb;   // block-uniform
    #pragma unroll
    for (int i = 0; i < 4; ++i)
        #pragma unroll
        for (int j = 0; j < 4; ++j) {
            int col = n0 + wn + j * 16 + l16;
            float bias = bqk[col];
            int gc = col & 511;
            #pragma unroll
            for (int r = 0; r < 4; ++r) {
                int grow = m0 + wm + i * 16 + quad * 4 + r;
                float v = acc[i][j][r] + bias;
                v = v > 0.f ? v + 1.f : __expf(v);   // elu(v)+1
                O[(size_t)grow * 512 + gc] = f2b(v);
            }
        }
}

// ---------------- kv via MFMA: kv[d][e] += sum_n kr[n,d]*v[n,e] -------------
// per (bh, chunk): 32x32 GEMM, K=512; channel-major LDS with bank rotation;
// 4 waves = 4 quadrants; atomicAdd into shared kvbuf (proven handoff).
__global__ __launch_bounds__(256)
void k_kv(const u16* __restrict__ Kb, const u16* __restrict__ Xb,
          float* __restrict__ kvbuf, float* __restrict__ ksum) {
    const int bh = blockIdx.x;            // 0..63
    const int b = bh >> 4, h = bh & 15;
    const int nb = blockIdx.y * 512;      // N chunk
    __shared__ u16 krT[32 * 72];          // [c][n], stride 72 (144B, 16B-align)
    __shared__ u16 vT[32 * 72];
    __shared__ float red[64 * 36];        // ksum reduce
    const int t = threadIdx.x;
    const int row = t >> 2;               // 0..63 staging row
    const int c8 = (t & 3) * 8;           // staging channel octet
    const int rot_w = 16 * ((c8 >> 3) & 3);   // bank rotation for writes
    const int lane = t & 63;
    const int wave = t >> 6;
    const int quad = lane >> 4;
    const int l16 = lane & 15;
    const int dq = (wave >> 1) * 16;      // d-quadrant base
    const int eq = (wave & 1) * 16;       // e-quadrant base
    const int ca = dq + l16;              // A channel (d)
    const int cb2 = eq + l16;             // B channel (e)
    const int rot_a = 16 * ((ca >> 3) & 3);
    const int rot_b = 16 * ((cb2 >> 3) & 3);

    float ksl[8] = {0, 0, 0, 0, 0, 0, 0, 0};
    f32x4 acc = {0.f, 0.f, 0.f, 0.f};

    float th[4];
    #pragma unroll
    for (int p = 0; p < 4; ++p)
        th[p] = exp2f(-THETA_SCALE * (float)(h * 16 + (c8 >> 1) + p));

    for (int pass = 0; pass < 8; ++pass) {
        int n = nb + pass * 64 + row;
        size_t base = (size_t)(b * 4096 + n) * 512 + h * 32 + c8;
        u16x8 k8 = *(const u16x8*)(Kb + base);
        u16x8 v8 = *(const u16x8*)(Xb + base);
        float kf[8], kr[8];
        #pragma unroll
        for (int j = 0; j < 8; ++j) kf[j] = b2f(k8[j]);
        #pragma unroll
        for (int p = 0; p < 4; ++p) {
            float sv, cv;
            sincosf((float)n * th[p], &sv, &cv);
            kr[2 * p]     = kf[2 * p] * cv - kf[2 * p + 1] * sv;
            kr[2 * p + 1] = kf[2 * p] * sv + kf[2 * p + 1] * cv;
        }
        #pragma unroll
        for (int j = 0; j < 8; ++j) ksl[j] += kf[j];
        if (pass) __syncthreads();
        int colw = (row + rot_w) & 63;    // rotated column
        #pragma unroll
        for (int j = 0; j < 8; ++j) {
            krT[(c8 + j) * 72 + colw] = f2b(kr[j]);
            vT[(c8 + j) * 72 + colw] = v8[j];
        }
        __syncthreads();
        #pragma unroll
        for (int ks = 0; ks < 64; ks += 32) {
            s16x8 a4 = *(const s16x8*)&krT[ca * 72 + ((ks + quad * 8 + rot_a) & 63)];
            s16x8 b4 = *(const s16x8*)&vT[cb2 * 72 + ((ks + quad * 8 + rot_b) & 63)];
            acc = __builtin_amdgcn_mfma_f32_16x16x32_bf16(a4, b4, acc, 0, 0, 0);
        }
    }

    // kv: D layout col=e=l16, row=d=quad*4+r ; device-scope atomic handoff
    #pragma unroll
    for (int r = 0; r < 4; ++r)
        atomicAdd(&kvbuf[(size_t)bh * 1024 + (dq + quad * 4 + r) * 32 + eq + l16],
                  acc[r]);

    // ksum reduce
    __syncthreads();
    *(float4*)&red[row * 36 + c8]     = make_float4(ksl[0], ksl[1], ksl[2], ksl[3]);
    *(float4*)&red[row * 36 + c8 + 4] = make_float4(ksl[4], ksl[5], ksl[6], ksl[7]);
    __syncthreads();
    if (t < 32) {
        float s = 0.f;
        for (int r = 0; r < 64; ++r) s += red[r * 36 + t];
        atomicAdd(&ksum[bh * 32 + t], s);
    }
}

// ---------------- out = z * (q_rope @ kv)/N + lepe (f32 to d_out) -----------
// phase 2 via MFMA: out[64x32] = qr[64x32] @ kv[32x32]; A = qr_s[row][d] bf16,
// B = kvT_s[e][d] bf16 (same [n][k] B-operand layout as the proven gemm);
// C round-trips LDS so the row-major lepe epilogue stays unchanged.
__global__ __launch_bounds__(256)
void k_out(const u16* __restrict__ Qb, const u16* __restrict__ Xb,
           const float* __restrict__ kvbuf, const float* __restrict__ ksum,
           const float* __restrict__ lw, const float* __restrict__ lb,
           float* __restrict__ OUT) {
    const int b = blockIdx.x >> 6;
    const int nb = (blockIdx.x & 63) * 64;
    const int hbase = blockIdx.y * 4;
    __shared__ u16 kvT_s[32 * 36];     // [e][d] bf16, stride 36
    __shared__ u16 qr_s[64 * 36];      // [row][d] bf16, stride 36
    __shared__ float out_s[64 * 36];   // [row][e] f32, stride 36
    __shared__ float ks_s[32];
    __shared__ float z_s[64];
    const int t = threadIdx.x;
    const int row = t >> 2;          // 0..63 local n
    const int c4 = t & 3;
    const int e0 = c4 * 8;
    const int lane = t & 63;
    const int wave = t >> 6;
    const int quad = lane >> 4;
    const int l16 = lane & 15;
    const float invN = 1.f / 4096.f;
    const int n = nb + row;
    const size_t rowbase = (size_t)(b * 4096 + n) * 512;

    for (int hh = 0; hh < 4; ++hh) {
        const int h = hbase + hh;
        const int bh = b * 16 + h;
        if (hh) __syncthreads();               // prev iteration LDS reads done
        // stage kvT (bf16, transposed) + kmean
        {
            int id = t * 4;                    // 0..1023, e varies fastest
            float4 kvv = *(const float4*)&kvbuf[(size_t)bh * 1024 + id];
            int d = id >> 5, e = id & 31;
            kvT_s[(e + 0) * 36 + d] = f2b(kvv.x * invN);
            kvT_s[(e + 1) * 36 + d] = f2b(kvv.y * invN);
            kvT_s[(e + 2) * 36 + d] = f2b(kvv.z * invN);
            kvT_s[(e + 3) * 36 + d] = f2b(kvv.w * invN);
        }
        if (t < 32) ks_s[t] = ksum[bh * 32 + t] * invN;
        __syncthreads();

        // phase 1: q (bf16), z partial dot, rope, stage qr bf16
        u16x8 q8 = *(const u16x8*)(Qb + rowbase + h * 32 + e0);
        float qf[8];
        #pragma unroll
        for (int j = 0; j < 8; ++j) qf[j] = b2f(q8[j]);
        float part = 0.f;
        #pragma unroll
        for (int j = 0; j < 8; ++j) part += qf[j] * ks_s[e0 + j];
        u16x8 qr8;
        #pragma unroll
        for (int p = 0; p < 4; ++p) {
            float th = exp2f(-THETA_SCALE * (float)(h * 16 + c4 * 4 + p));
            float sv, cv;
            sincosf((float)n * th, &sv, &cv);
            qr8[2 * p]     = f2b(qf[2 * p] * cv - qf[2 * p + 1] * sv);
            qr8[2 * p + 1] = f2b(qf[2 * p] * sv + qf[2 * p + 1] * cv);
        }
        *(u16x8*)&qr_s[row * 36 + e0] = qr8;
        part += __shfl_xor(part, 1);
        part += __shfl_xor(part, 2);
        if (c4 == 0) z_s[row] = 1.f / (part + 1e-6f);
        __syncthreads();

        // phase 2 (MFMA): wave = 16-row tile; 2 e-tiles; K=32 in one step
        {
            f32x4 zero4 = {0.f, 0.f, 0.f, 0.f};
            s16x8 a4 = *(const s16x8*)&qr_s[(wave * 16 + l16) * 36 + quad * 8];
            #pragma unroll
            for (int et = 0; et < 2; ++et) {
                s16x8 b4 = *(const s16x8*)&kvT_s[(et * 16 + l16) * 36 + quad * 8];
                f32x4 cacc = __builtin_amdgcn_mfma_f32_16x16x32_bf16(
                    a4, b4, zero4, 0, 0, 0);
                #pragma unroll
                for (int r = 0; r < 4; ++r)
                    out_s[(wave * 16 + quad * 4 + r) * 36 + et * 16 + l16] = cacc[r];
            }
        }
        __syncthreads();

        // epilogue: read out_s row-major, z scale + lepe + store f32
        const float z = z_s[row];
        float4 o0 = *(const float4*)&out_s[row * 36 + e0];
        float4 o1 = *(const float4*)&out_s[row * 36 + e0 + 4];
        float o[8] = {o0.x, o0.y, o0.z, o0.w, o1.x, o1.y, o1.z, o1.w};
        const int cb = h * 32 + e0;
        u16x8 xc = *(const u16x8*)(Xb + rowbase + cb);
        u16x8 xm = {0, 0, 0, 0, 0, 0, 0, 0};
        u16x8 xp = {0, 0, 0, 0, 0, 0, 0, 0};
        if (n > 0)    xm = *(const u16x8*)(Xb + rowbase - 512 + cb);
        if (n < 4095) xp = *(const u16x8*)(Xb + rowbase + 512 + cb);
        float rv[8];
        #pragma unroll
        for (int j = 0; j < 8; ++j) {
            int c = cb + j;
            float lep = b2f(xm[j]) * lw[c * 3] +
                        b2f(xc[j]) * lw[c * 3 + 1] +
                        b2f(xp[j]) * lw[c * 3 + 2] + lb[c];
            rv[j] = o[j] * z + lep;
        }
        float* Of = OUT + rowbase + cb;
        *(float4*)Of       = make_float4(rv[0], rv[1], rv[2], rv[3]);
        *(float4*)(Of + 4) = make_float4(rv[4], rv[5], rv[6], rv[7]);
    }
}

extern "C" void kernel_launch(void* const* d_in, const int* in_sizes, int n_in,
                              void* d_out, int out_size, void* d_ws, size_t ws_size,
                              hipStream_t stream) {
    const float* x   = (const float*)d_in[0];
    const float* Wqk = (const float*)d_in[1];
    const float* bqk = (const float*)d_in[2];
    const float* lw  = (const float*)d_in[3];
    const float* lb  = (const float*)d_in[4];
    float* out = (float*)d_out;

    // workspace (~49.3 MB); kvbuf+ksum contiguous (zeroed by k_prep tail)
    char* w = (char*)d_ws;
    u16* Kb      = (u16*)w;   w += (size_t)16384 * 512 * 2;   // 16 MB
    u16* Qb      = (u16*)w;   w += (size_t)16384 * 512 * 2;   // 16 MB
    u16* Xb      = (u16*)w;   w += (size_t)16384 * 512 * 2;   // 16 MB
    u16* WT      = (u16*)w;   w += (size_t)1024 * 512 * 2;    // 1 MB
    float* kvbuf = (float*)w; w += (size_t)64 * 1024 * 4;     // 256 KB
    float* ksum  = (float*)w;                                 // 8 KB (contig)

    k_prep<<<4674, 256, 0, stream>>>(x, Xb, Wqk, WT, kvbuf);
    k_gemm<<<dim3(128, 8), 256, 0, stream>>>(Xb, WT, bqk, Qb, Kb);
    k_kv<<<dim3(64, 8), 256, 0, stream>>>(Kb, Xb, kvbuf, ksum);
    k_out<<<dim3(256, 4), 256, 0, stream>>>(Qb, Xb, kvbuf, ksum, lw, lb, out);
}